// Round 8
// baseline (248.451 us; speedup 1.0000x reference)
//
#include <hip/hip_runtime.h>

typedef unsigned short u16;
typedef __attribute__((ext_vector_type(8))) short short8;
typedef __attribute__((ext_vector_type(8))) unsigned short ushort8_t;
typedef __attribute__((ext_vector_type(4))) float f32x4;
typedef __attribute__((ext_vector_type(2))) float v2f;

#define BATCH   16
#define CCH     512
#define NBOX    36
#define SS      26
#define INDIM   25088   // 512*49
#define HIDN    512
#define M_ROWS  576     // BATCH*NBOX
#define KSPLIT  56
#define KITERS  7       // per split, BK=64 -> 56*7*64 = 25088
#define NKB     392     // total K-blocks of 64 (pixel-major k = p*512 + c)

__device__ __forceinline__ u16 f2bf(float f) {
  unsigned u = __float_as_uint(f);
  u += 0x7FFF + ((u >> 16) & 1);   // RNE
  return (u16)(u >> 16);
}
__device__ __forceinline__ float bf2f(u16 h) {
  return __uint_as_float(((unsigned)h) << 16);
}
__device__ __forceinline__ v2f bf2x2(u16 a, u16 b) {
  v2f r;
  r.x = __uint_as_float(((unsigned)a) << 16);
  r.y = __uint_as_float(((unsigned)b) << 16);
  return r;
}

// ---------------- kernel 1: transpose lf (B,C,H,W) f32 -> (B,HW,C) bf16 ----
__global__ __launch_bounds__(256) void k_transpose_lf(const float* __restrict__ in,
                                                      u16* __restrict__ out) {
  __shared__ u16 t[32][66];
  int b = blockIdx.z, y = blockIdx.y, ct = blockIdx.x;  // c0 = ct*64
  int tid = threadIdx.x;

  int cl = tid >> 2;            // 0..63 channel within tile
  int xq = (tid & 3) * 8;       // 8 consecutive x
  const float* src = in + ((size_t)(b * CCH + ct * 64 + cl) * 1024) + y * 32 + xq;
  float4 v0 = *(const float4*)src;
  float4 v1 = *(const float4*)(src + 4);
  t[xq + 0][cl] = f2bf(v0.x); t[xq + 1][cl] = f2bf(v0.y);
  t[xq + 2][cl] = f2bf(v0.z); t[xq + 3][cl] = f2bf(v0.w);
  t[xq + 4][cl] = f2bf(v1.x); t[xq + 5][cl] = f2bf(v1.y);
  t[xq + 6][cl] = f2bf(v1.z); t[xq + 7][cl] = f2bf(v1.w);
  __syncthreads();

  int xl = tid >> 3;            // 0..31
  int cq = (tid & 7) * 8;       // 8 consecutive channels
  ushort8_t o;
#pragma unroll
  for (int i = 0; i < 8; ++i) o[i] = t[xl][cq + i];
  *(ushort8_t*)(out + ((size_t)b * 1024 + y * 32 + xl) * CCH + ct * 64 + cq) = o;
}

// ---------------- kernel 2: roi_fc_W f32 -> Wb2[kb][h][64] bf16 ------------
#define WPAD 532
__global__ __launch_bounds__(256) void k_convert_w(const float* __restrict__ in,
                                                   u16* __restrict__ out) {
  __shared__ u16 s[49 * WPAD];   // 52136 B
  int h = blockIdx.x;
  int tid = threadIdx.x;
  const float4* src = (const float4*)(in + (size_t)h * INDIM);  // 6272 float4
  for (int i = tid; i < 6272; i += 256) {
    float4 v = src[i];
    int k = i * 4;
#pragma unroll
    for (int j = 0; j < 4; ++j) {
      int kk = k + j;
      int c = kk / 49;          // const divide -> magic mul
      int p = kk - c * 49;
      s[p * WPAD + c] = f2bf((&v.x)[j]);
    }
  }
  __syncthreads();
  // 3136 ushort8 chunks: q -> p = q>>6, c0 = (q&63)*8
  for (int q = tid; q < 3136; q += 256) {
    int p = q >> 6;
    int c0 = (q & 63) * 8;
    const u16* sp = &s[p * WPAD + c0];
    ushort8_t o;
#pragma unroll
    for (int i = 0; i < 8; ++i) o[i] = sp[i];
    int kb = p * 8 + (c0 >> 6);
    int col = c0 & 63;
    *(ushort8_t*)(out + ((size_t)kb * HIDN + h) * 64 + col) = o;
  }
}

// ---------------- kernel 3: ROI align -> flat2[kb][box][64] bf16 -----------
__global__ __launch_bounds__(512) void k_roi(const u16* __restrict__ lf_t,
                                             const float* __restrict__ pred,
                                             u16* __restrict__ flat2) {
  __shared__ int   s_ylo[14], s_yhi[14], s_xlo[14], s_xhi[14];
  __shared__ float s_wyl[14], s_wyh[14], s_wxl[14], s_wxh[14];

  int blk = blockIdx.x;
  int b = blk / NBOX, n = blk % NBOX;
  int t = threadIdx.x;

  if (t < 28) {
    bool isY = t < 14;
    int j = isY ? t : t - 14;
    float c0, c1, c2, c3;
    if (n < SS) {
      const float* p = pred + ((size_t)(b * SS + n)) * 4;
      c0 = p[0]; c1 = p[1]; c2 = p[2]; c3 = p[3];
    } else { c0 = 0.f; c1 = 0.f; c2 = 1.f; c3 = 1.f; }
    float lo1 = (isY ? c1 : c0) * 32.f;
    float hi1 = (isY ? c3 : c2) * 32.f;
    float sz = fmaxf(hi1 - lo1, 1.f);
    float bs = sz * (1.f / 7.f);
    float off = (float)(j >> 1) + 0.25f + 0.5f * (float)(j & 1);
    float pos = lo1 + off * bs;
    bool valid = (pos > -1.f) && (pos < 32.f);
    float tc = fminf(fmaxf(pos, 0.f), 31.f);
    int lo = (int)floorf(tc);
    int hi = min(lo + 1, 31);
    float fr = tc - (float)lo;
    float wl = valid ? (1.f - fr) : 0.f;
    float wh = valid ? fr : 0.f;
    if (isY) { s_ylo[j] = lo; s_yhi[j] = hi; s_wyl[j] = wl; s_wyh[j] = wh; }
    else     { s_xlo[j] = lo; s_xhi[j] = hi; s_wxl[j] = wl; s_wxh[j] = wh; }
  }
  __syncthreads();

  int cg = t & 63;          // channel group: channels cg*8 .. cg*8+7
  int pg = t >> 6;          // pixel stripe: pixels pg, pg+8, ...
  const u16* base = lf_t + (size_t)b * 1024 * CCH + cg * 8;

  for (int p = pg; p < 49; p += 8) {
    int py = p / 7, px = p % 7;
    v2f a0 = {0.f, 0.f}, a1 = {0.f, 0.f}, a2 = {0.f, 0.f}, a3 = {0.f, 0.f};
#pragma unroll
    for (int sy = 0; sy < 2; ++sy) {
      int jy = 2 * py + sy;
      const u16* rlo = base + s_ylo[jy] * 32 * CCH;
      const u16* rhi = base + s_yhi[jy] * 32 * CCH;
      float wyl = s_wyl[jy], wyh = s_wyh[jy];
#pragma unroll
      for (int sx = 0; sx < 2; ++sx) {
        int jx = 2 * px + sx;
        int xl = s_xlo[jx] * CCH, xh = s_xhi[jx] * CCH;
        v2f wll = {wyl * s_wxl[jx], wyl * s_wxl[jx]};
        v2f wlh = {wyl * s_wxh[jx], wyl * s_wxh[jx]};
        v2f whl = {wyh * s_wxl[jx], wyh * s_wxl[jx]};
        v2f whh = {wyh * s_wxh[jx], wyh * s_wxh[jx]};
        ushort8_t vll = *(const ushort8_t*)(rlo + xl);
        ushort8_t vlh = *(const ushort8_t*)(rlo + xh);
        ushort8_t vhl = *(const ushort8_t*)(rhi + xl);
        ushort8_t vhh = *(const ushort8_t*)(rhi + xh);
        a0 += wll * bf2x2(vll[0], vll[1]) + wlh * bf2x2(vlh[0], vlh[1])
            + whl * bf2x2(vhl[0], vhl[1]) + whh * bf2x2(vhh[0], vhh[1]);
        a1 += wll * bf2x2(vll[2], vll[3]) + wlh * bf2x2(vlh[2], vlh[3])
            + whl * bf2x2(vhl[2], vhl[3]) + whh * bf2x2(vhh[2], vhh[3]);
        a2 += wll * bf2x2(vll[4], vll[5]) + wlh * bf2x2(vlh[4], vlh[5])
            + whl * bf2x2(vhl[4], vhl[5]) + whh * bf2x2(vhh[4], vhh[5]);
        a3 += wll * bf2x2(vll[6], vll[7]) + wlh * bf2x2(vlh[6], vlh[7])
            + whl * bf2x2(vhl[6], vhl[7]) + whh * bf2x2(vhh[6], vhh[7]);
      }
    }
    ushort8_t o;
    o[0] = f2bf(a0.x * 0.25f); o[1] = f2bf(a0.y * 0.25f);
    o[2] = f2bf(a1.x * 0.25f); o[3] = f2bf(a1.y * 0.25f);
    o[4] = f2bf(a2.x * 0.25f); o[5] = f2bf(a2.y * 0.25f);
    o[6] = f2bf(a3.x * 0.25f); o[7] = f2bf(a3.y * 0.25f);
    int kb = p * 8 + (cg >> 3);
    int col = (cg & 7) * 8;
    *(ushort8_t*)(flat2 + ((size_t)kb * M_ROWS + blk) * 64 + col) = o;
  }
}

// ---------------- kernel 4: GEMM, split-K, bf16 MFMA -----------------------
// v7: no-LDS dataflow (R6) + KSPLIT 28->56. R6 diagnosis: ~1280 cyc per
// wave-kt vs ~160 cyc MFMA — pure L3-latency bound at 2 waves/SIMD (the
// 55 MB A+B working set misses the 4 MB per-XCD L2). 1008 blocks = 4032
// waves = 4 waves/SIMD doubles latency overlap. Partials in bf16 to keep
// traffic & workspace identical to KSPLIT=28 fp32 (err +~6e-3 << 0.084).
__global__ __launch_bounds__(256) void k_gemm(const u16* __restrict__ flat2,
                                              const u16* __restrict__ Wb2,
                                              u16* __restrict__ partials) {
  int tid = threadIdx.x;
  int wave = tid >> 6, lane = tid & 63;
  int quad = lane >> 4, r = lane & 15;

  int m0 = blockIdx.y * 64;
  int n0 = (blockIdx.x * 4 + wave) * 64;
  int kb0 = blockIdx.z * KITERS;

  f32x4 acc[4][4];
#pragma unroll
  for (int mi = 0; mi < 4; ++mi)
#pragma unroll
    for (int ni = 0; ni < 4; ++ni) acc[mi][ni] = (f32x4){0.f, 0.f, 0.f, 0.f};

  // lane-fixed fragment bases (row = m0/n0 + r, k-offset = quad*8)
  const u16* aB = flat2 + ((size_t)kb0 * M_ROWS + m0 + r) * 64 + quad * 8;
  const u16* bB = Wb2  + ((size_t)kb0 * HIDN  + n0 + r) * 64 + quad * 8;

#pragma unroll 2
  for (int kt = 0; kt < KITERS; ++kt) {
    const u16* a = aB + (size_t)kt * (M_ROWS * 64);
    const u16* b = bB + (size_t)kt * (HIDN * 64);
    short8 af[2][4], bfr[2][4];
#pragma unroll
    for (int mi = 0; mi < 4; ++mi) {
      af[0][mi] = *(const short8*)(a + mi * 1024);        // kk = 0..31
      af[1][mi] = *(const short8*)(a + mi * 1024 + 32);   // kk = 32..63
    }
#pragma unroll
    for (int ni = 0; ni < 4; ++ni) {
      bfr[0][ni] = *(const short8*)(b + ni * 1024);
      bfr[1][ni] = *(const short8*)(b + ni * 1024 + 32);
    }
#pragma unroll
    for (int kk = 0; kk < 2; ++kk)
#pragma unroll
      for (int mi = 0; mi < 4; ++mi)
#pragma unroll
        for (int ni = 0; ni < 4; ++ni)
          acc[mi][ni] = __builtin_amdgcn_mfma_f32_16x16x32_bf16(
              af[kk][mi], bfr[kk][ni], acc[mi][ni], 0, 0, 0);
  }

  u16* part = partials + (size_t)blockIdx.z * (M_ROWS * HIDN);
#pragma unroll
  for (int mi = 0; mi < 4; ++mi)
#pragma unroll
    for (int ni = 0; ni < 4; ++ni) {
      int row0 = m0 + mi * 16 + quad * 4;
      int col = n0 + ni * 16 + r;
#pragma unroll
      for (int reg = 0; reg < 4; ++reg)
        part[(size_t)(row0 + reg) * HIDN + col] = f2bf(acc[mi][ni][reg]);
    }
}

// ---------------- kernel 5: reduce split-K(bf16) + bias + relu -> feats ----
__global__ __launch_bounds__(256) void k_reduce(const u16* __restrict__ partials,
                                                const float* __restrict__ bias,
                                                float* __restrict__ feats) {
  int gid = blockIdx.x * 256 + threadIdx.x;   // < 576*512/8 = 36864
  int row = gid >> 6;
  int c0 = (gid & 63) * 8;
  float s[8] = {0.f, 0.f, 0.f, 0.f, 0.f, 0.f, 0.f, 0.f};
  const u16* p = partials + (size_t)row * HIDN + c0;
  for (int z = 0; z < KSPLIT; ++z) {
    ushort8_t v = *(const ushort8_t*)(p + (size_t)z * (M_ROWS * HIDN));
#pragma unroll
    for (int j = 0; j < 8; ++j) s[j] += bf2f(v[j]);
  }
  float4 o0, o1;
  const float* bi = bias + c0;
  o0.x = fmaxf(s[0] + bi[0], 0.f); o0.y = fmaxf(s[1] + bi[1], 0.f);
  o0.z = fmaxf(s[2] + bi[2], 0.f); o0.w = fmaxf(s[3] + bi[3], 0.f);
  o1.x = fmaxf(s[4] + bi[4], 0.f); o1.y = fmaxf(s[5] + bi[5], 0.f);
  o1.z = fmaxf(s[6] + bi[6], 0.f); o1.w = fmaxf(s[7] + bi[7], 0.f);
  float* dst = feats + (size_t)row * HIDN + c0;
  *(float4*)dst = o0;
  *(float4*)(dst + 4) = o1;
}

// ---------------- kernel 6: all heads, one wave per output dot -------------
__device__ __forceinline__ float wave_red(float s) {
#pragma unroll
  for (int off = 32; off > 0; off >>= 1) s += __shfl_down(s, off);
  return s;
}

__device__ __forceinline__ float dot512(const float* __restrict__ f,
                                        const float* __restrict__ w, int lane) {
  const float4* f4 = (const float4*)f;
  const float4* w4 = (const float4*)w;
  float4 x0 = f4[lane], y0 = w4[lane];
  float4 x1 = f4[lane + 64], y1 = w4[lane + 64];
  return x0.x * y0.x + x0.y * y0.y + x0.z * y0.z + x0.w * y0.w +
         x1.x * y1.x + x1.y * y1.y + x1.z * y1.z + x1.w * y1.w;
}

__global__ __launch_bounds__(256) void k_heads(const float* __restrict__ feats,
                                               const float* __restrict__ pred,
                                               const float* __restrict__ cW,
                                               const float* __restrict__ cb,
                                               const float* __restrict__ pW,
                                               const float* __restrict__ pb,
                                               const float* __restrict__ lW,
                                               const float* __restrict__ lb,
                                               const float* __restrict__ gW,
                                               const float* __restrict__ gb,
                                               const int* __restrict__ lidx,
                                               const int* __restrict__ gidx,
                                               float* __restrict__ out) {
  int wid = blockIdx.x * 4 + (threadIdx.x >> 6);   // 0..4639
  int lane = threadIdx.x & 63;
  float sum = 0.f;

  if (wid < 1664) {                 // refined (B,26,4)
    int b = wid / 104, rr = wid % 104, s = rr >> 2, o = rr & 3;
    sum = dot512(feats + (size_t)(b * NBOX + s) * HIDN,
                 cW + (size_t)(s * 4 + o) * HIDN, lane);
    sum = wave_red(sum);
    if (lane == 0) {
      const float* p = pred + (size_t)(b * SS + s) * 4;
      float wdt = p[2] - p[0], hgt = p[3] - p[1];
      float whv = (o & 1) ? hgt : wdt;
      out[wid] = p[o] + (sum + cb[s * 4 + o]) * whv;
    }
  } else if (wid < 2080) {          // presence (B,26)
    int i = wid - 1664;
    int b = i / 26, s = i % 26;
    sum = dot512(feats + (size_t)(b * NBOX + s) * HIDN,
                 pW + (size_t)s * HIDN, lane);
    sum = wave_red(sum);
    if (lane == 0) out[1664 + i] = sum + pb[s];
  } else if (wid < 3616) {          // loc (B,12,8)
    int i = wid - 2080;
    int b = i / 96, rr = i % 96, l = rr >> 3, o = rr & 7;
    sum = dot512(feats + (size_t)(b * NBOX + lidx[l]) * HIDN,
                 lW + (size_t)(l * 8 + o) * HIDN, lane);
    sum = wave_red(sum);
    if (lane == 0) out[2080 + b * 160 + rr] = sum + lb[l * 8 + o];
  } else {                          // grp (B,4,16), K = 6*512
    int i = wid - 3616;
    int b = i / 64, rr = i % 64, g = rr >> 4, o = rr & 15;
    const float* w = gW + (size_t)(g * 16 + o) * 3072;
#pragma unroll
    for (int jj = 0; jj < 6; ++jj) {
      sum += dot512(feats + (size_t)(b * NBOX + gidx[g * 6 + jj]) * HIDN,
                    w + jj * 512, lane);
    }
    sum = wave_red(sum);
    if (lane == 0) out[2080 + b * 160 + 96 + rr] = sum + gb[g * 16 + o];
  }
}

// ---------------------------------------------------------------------------
extern "C" void kernel_launch(void* const* d_in, const int* in_sizes, int n_in,
                              void* d_out, int out_size, void* d_ws, size_t ws_size,
                              hipStream_t stream) {
  const float* lf      = (const float*)d_in[0];
  const float* pred    = (const float*)d_in[1];
  const float* roiW    = (const float*)d_in[2];
  const float* roiB    = (const float*)d_in[3];
  const float* cW      = (const float*)d_in[4];
  const float* cb      = (const float*)d_in[5];
  const float* pW      = (const float*)d_in[6];
  const float* pb      = (const float*)d_in[7];
  const float* lW      = (const float*)d_in[8];
  const float* lb      = (const float*)d_in[9];
  const float* gW      = (const float*)d_in[10];
  const float* gb      = (const float*)d_in[11];
  const int*   lidx    = (const int*)d_in[12];
  const int*   gidx    = (const int*)d_in[13];
  float* out = (float*)d_out;

  char* ws = (char*)d_ws;
  // region 0: lf_t (16.8 MB) then reused by partials bf16 (33.0 MB = 56*576*512*2)
  u16*   lf_t     = (u16*)ws;
  u16*   partials = (u16*)ws;
  u16*   Wb2   = (u16*)(ws + 33030144);                 // 25,690,112 B
  u16*   flat2 = (u16*)(ws + 33030144 + 25690112);      // 28,901,376 B
  float* feats = (float*)(ws + 33030144 + 25690112 + 28901376); // 1,179,648 B

  k_transpose_lf<<<dim3(8, 32, 16), 256, 0, stream>>>(lf, lf_t);
  k_convert_w<<<HIDN, 256, 0, stream>>>(roiW, Wb2);
  k_roi<<<576, 512, 0, stream>>>(lf_t, pred, flat2);
  // NOTE: partials aliases lf_t's region; k_roi (last reader of lf_t) is
  // stream-ordered before k_gemm (first writer of partials).
  k_gemm<<<dim3(2, 9, KSPLIT), 256, 0, stream>>>(flat2, Wb2, partials);
  k_reduce<<<(M_ROWS * HIDN / 8) / 256, 256, 0, stream>>>(partials, roiB, feats);
  k_heads<<<1160, 256, 0, stream>>>(feats, pred, cW, cb, pW, pb, lW, lb, gW, gb,
                                    lidx, gidx, out);
}

// Round 9
// 217.866 us; speedup vs baseline: 1.1404x; 1.1404x over previous
//
#include <hip/hip_runtime.h>

typedef unsigned short u16;
typedef __attribute__((ext_vector_type(8))) short short8;
typedef __attribute__((ext_vector_type(8))) unsigned short ushort8_t;
typedef __attribute__((ext_vector_type(4))) float f32x4;
typedef __attribute__((ext_vector_type(2))) float v2f;

#define BATCH   16
#define CCH     512
#define NBOX    36
#define SS      26
#define INDIM   25088   // 512*49
#define HIDN    512
#define M_ROWS  576     // BATCH*NBOX
#define KSPLIT  56
#define KITERS  7       // per split, BK=64 -> 56*7*64 = 25088
#define NKB     392     // total K-blocks of 64 (pixel-major k = p*512 + c)

__device__ __forceinline__ u16 f2bf(float f) {
  unsigned u = __float_as_uint(f);
  u += 0x7FFF + ((u >> 16) & 1);   // RNE
  return (u16)(u >> 16);
}
__device__ __forceinline__ float bf2f(u16 h) {
  return __uint_as_float(((unsigned)h) << 16);
}
__device__ __forceinline__ v2f bf2x2(u16 a, u16 b) {
  v2f r;
  r.x = __uint_as_float(((unsigned)a) << 16);
  r.y = __uint_as_float(((unsigned)b) << 16);
  return r;
}

// ---------------- kernel 1: transpose lf (B,C,H,W) f32 -> (B,HW,C) bf16 ----
__global__ __launch_bounds__(256) void k_transpose_lf(const float* __restrict__ in,
                                                      u16* __restrict__ out) {
  __shared__ u16 t[32][66];
  int b = blockIdx.z, y = blockIdx.y, ct = blockIdx.x;  // c0 = ct*64
  int tid = threadIdx.x;

  int cl = tid >> 2;            // 0..63 channel within tile
  int xq = (tid & 3) * 8;       // 8 consecutive x
  const float* src = in + ((size_t)(b * CCH + ct * 64 + cl) * 1024) + y * 32 + xq;
  float4 v0 = *(const float4*)src;
  float4 v1 = *(const float4*)(src + 4);
  t[xq + 0][cl] = f2bf(v0.x); t[xq + 1][cl] = f2bf(v0.y);
  t[xq + 2][cl] = f2bf(v0.z); t[xq + 3][cl] = f2bf(v0.w);
  t[xq + 4][cl] = f2bf(v1.x); t[xq + 5][cl] = f2bf(v1.y);
  t[xq + 6][cl] = f2bf(v1.z); t[xq + 7][cl] = f2bf(v1.w);
  __syncthreads();

  int xl = tid >> 3;            // 0..31
  int cq = (tid & 7) * 8;       // 8 consecutive channels
  ushort8_t o;
#pragma unroll
  for (int i = 0; i < 8; ++i) o[i] = t[xl][cq + i];
  *(ushort8_t*)(out + ((size_t)b * 1024 + y * 32 + xl) * CCH + ct * 64 + cq) = o;
}

// ---------------- kernel 2: roi_fc_W f32 -> Wb2[kb][h][64] bf16 ------------
#define WPAD 532
__global__ __launch_bounds__(256) void k_convert_w(const float* __restrict__ in,
                                                   u16* __restrict__ out) {
  __shared__ u16 s[49 * WPAD];   // 52136 B
  int h = blockIdx.x;
  int tid = threadIdx.x;
  const float4* src = (const float4*)(in + (size_t)h * INDIM);  // 6272 float4
  for (int i = tid; i < 6272; i += 256) {
    float4 v = src[i];
    int k = i * 4;
#pragma unroll
    for (int j = 0; j < 4; ++j) {
      int kk = k + j;
      int c = kk / 49;          // const divide -> magic mul
      int p = kk - c * 49;
      s[p * WPAD + c] = f2bf((&v.x)[j]);
    }
  }
  __syncthreads();
  // 3136 ushort8 chunks: q -> p = q>>6, c0 = (q&63)*8
  for (int q = tid; q < 3136; q += 256) {
    int p = q >> 6;
    int c0 = (q & 63) * 8;
    const u16* sp = &s[p * WPAD + c0];
    ushort8_t o;
#pragma unroll
    for (int i = 0; i < 8; ++i) o[i] = sp[i];
    int kb = p * 8 + (c0 >> 6);
    int col = c0 & 63;
    *(ushort8_t*)(out + ((size_t)kb * HIDN + h) * 64 + col) = o;
  }
}

// ---------------- kernel 3: ROI align -> flat2[kb][box][64] bf16 -----------
// v5: XCD-locality swizzle. R8 diagnosis: this kernel issues ~529 MB of tap
// load requests; with blocks round-robined across XCDs each 4 MB L2 touches
// all 16 images (16 MB) -> L3-served at the ~7 TB/s fabric ceiling. Now XCD
// (bid&7) owns images {2*xcd, 2*xcd+1} (2 MB, L2-resident).
__global__ __launch_bounds__(512) void k_roi(const u16* __restrict__ lf_t,
                                             const float* __restrict__ pred,
                                             u16* __restrict__ flat2) {
  __shared__ int   s_ylo[14], s_yhi[14], s_xlo[14], s_xhi[14];
  __shared__ float s_wyl[14], s_wyh[14], s_wxl[14], s_wxh[14];

  int bid = blockIdx.x;
  int xcd = bid & 7;
  int s = bid >> 3;              // 0..71
  int b = xcd * 2 + (s >= 36 ? 1 : 0);
  int n = (s >= 36) ? s - 36 : s;
  int blk = b * NBOX + n;        // output row (layout unchanged)
  int t = threadIdx.x;

  if (t < 28) {
    bool isY = t < 14;
    int j = isY ? t : t - 14;
    float c0, c1, c2, c3;
    if (n < SS) {
      const float* p = pred + ((size_t)(b * SS + n)) * 4;
      c0 = p[0]; c1 = p[1]; c2 = p[2]; c3 = p[3];
    } else { c0 = 0.f; c1 = 0.f; c2 = 1.f; c3 = 1.f; }
    float lo1 = (isY ? c1 : c0) * 32.f;
    float hi1 = (isY ? c3 : c2) * 32.f;
    float sz = fmaxf(hi1 - lo1, 1.f);
    float bs = sz * (1.f / 7.f);
    float off = (float)(j >> 1) + 0.25f + 0.5f * (float)(j & 1);
    float pos = lo1 + off * bs;
    bool valid = (pos > -1.f) && (pos < 32.f);
    float tc = fminf(fmaxf(pos, 0.f), 31.f);
    int lo = (int)floorf(tc);
    int hi = min(lo + 1, 31);
    float fr = tc - (float)lo;
    float wl = valid ? (1.f - fr) : 0.f;
    float wh = valid ? fr : 0.f;
    if (isY) { s_ylo[j] = lo; s_yhi[j] = hi; s_wyl[j] = wl; s_wyh[j] = wh; }
    else     { s_xlo[j] = lo; s_xhi[j] = hi; s_wxl[j] = wl; s_wxh[j] = wh; }
  }
  __syncthreads();

  int cg = t & 63;          // channel group: channels cg*8 .. cg*8+7
  int pg = t >> 6;          // pixel stripe: pixels pg, pg+8, ...
  const u16* base = lf_t + (size_t)b * 1024 * CCH + cg * 8;

  for (int p = pg; p < 49; p += 8) {
    int py = p / 7, px = p % 7;
    v2f a0 = {0.f, 0.f}, a1 = {0.f, 0.f}, a2 = {0.f, 0.f}, a3 = {0.f, 0.f};
#pragma unroll
    for (int sy = 0; sy < 2; ++sy) {
      int jy = 2 * py + sy;
      const u16* rlo = base + s_ylo[jy] * 32 * CCH;
      const u16* rhi = base + s_yhi[jy] * 32 * CCH;
      float wyl = s_wyl[jy], wyh = s_wyh[jy];
#pragma unroll
      for (int sx = 0; sx < 2; ++sx) {
        int jx = 2 * px + sx;
        int xl = s_xlo[jx] * CCH, xh = s_xhi[jx] * CCH;
        v2f wll = {wyl * s_wxl[jx], wyl * s_wxl[jx]};
        v2f wlh = {wyl * s_wxh[jx], wyl * s_wxh[jx]};
        v2f whl = {wyh * s_wxl[jx], wyh * s_wxl[jx]};
        v2f whh = {wyh * s_wxh[jx], wyh * s_wxh[jx]};
        ushort8_t vll = *(const ushort8_t*)(rlo + xl);
        ushort8_t vlh = *(const ushort8_t*)(rlo + xh);
        ushort8_t vhl = *(const ushort8_t*)(rhi + xl);
        ushort8_t vhh = *(const ushort8_t*)(rhi + xh);
        a0 += wll * bf2x2(vll[0], vll[1]) + wlh * bf2x2(vlh[0], vlh[1])
            + whl * bf2x2(vhl[0], vhl[1]) + whh * bf2x2(vhh[0], vhh[1]);
        a1 += wll * bf2x2(vll[2], vll[3]) + wlh * bf2x2(vlh[2], vlh[3])
            + whl * bf2x2(vhl[2], vhl[3]) + whh * bf2x2(vhh[2], vhh[3]);
        a2 += wll * bf2x2(vll[4], vll[5]) + wlh * bf2x2(vlh[4], vlh[5])
            + whl * bf2x2(vhl[4], vhl[5]) + whh * bf2x2(vhh[4], vhh[5]);
        a3 += wll * bf2x2(vll[6], vll[7]) + wlh * bf2x2(vlh[6], vlh[7])
            + whl * bf2x2(vhl[6], vhl[7]) + whh * bf2x2(vhh[6], vhh[7]);
      }
    }
    ushort8_t o;
    o[0] = f2bf(a0.x * 0.25f); o[1] = f2bf(a0.y * 0.25f);
    o[2] = f2bf(a1.x * 0.25f); o[3] = f2bf(a1.y * 0.25f);
    o[4] = f2bf(a2.x * 0.25f); o[5] = f2bf(a2.y * 0.25f);
    o[6] = f2bf(a3.x * 0.25f); o[7] = f2bf(a3.y * 0.25f);
    int kb = p * 8 + (cg >> 3);
    int col = (cg & 7) * 8;
    *(ushort8_t*)(flat2 + ((size_t)kb * M_ROWS + blk) * 64 + col) = o;
  }
}

// ---------------- kernel 4: GEMM, split-K, bf16 MFMA -----------------------
// v8: R5 LDS structure (128x128 tile, register pipeline, XOR swizzle) +
// KSPLIT 56 + bf16 partials + XCD-locality z-mapping. R8 diagnosis: all
// prior GEMMs saturate ~7 TB/s of L3/fabric requests because A/B re-reads
// (x4-x9) miss the 4 MB per-XCD L2 (blocks sharing data scattered across
// XCDs). Now XCD (bid&7) owns z-slices [xcd*7, xcd*7+7): per-z A+B slices
// ~1 MB -> re-reads served from local L2 at 34.5 TB/s aggregate.
__global__ __launch_bounds__(256) void k_gemm(const u16* __restrict__ flat2,
                                              const u16* __restrict__ Wb2,
                                              u16* __restrict__ partials) {
  __shared__ u16 As[128 * 64];   // 16 KB
  __shared__ u16 Bs[128 * 64];   // 16 KB

  int tid = threadIdx.x;
  int wave = tid >> 6, lane = tid & 63;
  int wm = wave >> 1, wn = wave & 1;
  int quad = lane >> 4, r = lane & 15;
  int xb = r & 7;                       // read-side XOR key

  // XCD-owner decode: 1120 blocks = 8 XCDs x 7 z x 20 (x,y)
  int bid = blockIdx.x;
  int xcd = bid & 7;
  int slot = bid >> 3;                  // 0..139
  int z = xcd * 7 + slot / 20;          // 0..55
  int xy = slot % 20;
  int tileN0 = (xy & 3) * 128;
  int tileM0 = (xy >> 2) * 128;
  int kb0 = z * KITERS;

  size_t aoff[4], boff[4];
  int    ldso[4];
#pragma unroll
  for (int t = 0; t < 4; ++t) {
    int chunk = (wave * 4 + t) * 64 + lane;
    int row = chunk >> 3;
    int lc = chunk & 7;
    ldso[t] = row * 64 + ((lc ^ (row & 7)) << 3);
    int grow = min(tileM0 + row, M_ROWS - 1);     // clamp M tail
    aoff[t] = ((size_t)kb0 * M_ROWS + grow) * 64 + lc * 8;
    boff[t] = ((size_t)kb0 * HIDN + tileN0 + row) * 64 + lc * 8;
  }

  f32x4 acc[4][4];
#pragma unroll
  for (int mi = 0; mi < 4; ++mi)
#pragma unroll
    for (int ni = 0; ni < 4; ++ni) acc[mi][ni] = (f32x4){0.f, 0.f, 0.f, 0.f};

  short8 ra[4], rb[4];
#pragma unroll
  for (int t = 0; t < 4; ++t) {
    ra[t] = *(const short8*)(flat2 + aoff[t]);
    rb[t] = *(const short8*)(Wb2 + boff[t]);
  }

  for (int kt = 0; kt < KITERS; ++kt) {
    // commit current registers to LDS (vmcnt wait lands here, overlapped)
#pragma unroll
    for (int t = 0; t < 4; ++t) {
      *(short8*)&As[ldso[t]] = ra[t];
      *(short8*)&Bs[ldso[t]] = rb[t];
    }
    __syncthreads();

    // issue next tile's global loads (stay in flight through compute)
    if (kt + 1 < KITERS) {
      size_t ak = (size_t)(kt + 1) * (M_ROWS * 64);
      size_t bk = (size_t)(kt + 1) * (HIDN * 64);
#pragma unroll
      for (int t = 0; t < 4; ++t) {
        ra[t] = *(const short8*)(flat2 + aoff[t] + ak);
        rb[t] = *(const short8*)(Wb2 + boff[t] + bk);
      }
    }

    // compute on the committed tile
#pragma unroll
    for (int kk = 0; kk < 64; kk += 32) {
      int k8 = kk >> 3;                 // 0 or 4
      int pc = ((k8 + quad) ^ xb) << 3; // physical column (u16 units)
      short8 af[4], bfr[4];
#pragma unroll
      for (int mi = 0; mi < 4; ++mi)
        af[mi] = *(const short8*)&As[(wm * 64 + mi * 16 + r) * 64 + pc];
#pragma unroll
      for (int ni = 0; ni < 4; ++ni)
        bfr[ni] = *(const short8*)&Bs[(wn * 64 + ni * 16 + r) * 64 + pc];
#pragma unroll
      for (int mi = 0; mi < 4; ++mi)
#pragma unroll
        for (int ni = 0; ni < 4; ++ni)
          acc[mi][ni] = __builtin_amdgcn_mfma_f32_16x16x32_bf16(
              af[mi], bfr[ni], acc[mi][ni], 0, 0, 0);
    }
    __syncthreads();
  }

  u16* part = partials + (size_t)z * (M_ROWS * HIDN);
#pragma unroll
  for (int mi = 0; mi < 4; ++mi)
#pragma unroll
    for (int ni = 0; ni < 4; ++ni) {
      int row0 = tileM0 + wm * 64 + mi * 16 + quad * 4;
      int col = tileN0 + wn * 64 + ni * 16 + r;
#pragma unroll
      for (int reg = 0; reg < 4; ++reg) {
        int row = row0 + reg;
        if (row < M_ROWS) part[(size_t)row * HIDN + col] = f2bf(acc[mi][ni][reg]);
      }
    }
}

// ---------------- kernel 5: reduce split-K(bf16) + bias + relu -> feats ----
__global__ __launch_bounds__(256) void k_reduce(const u16* __restrict__ partials,
                                                const float* __restrict__ bias,
                                                float* __restrict__ feats) {
  int gid = blockIdx.x * 256 + threadIdx.x;   // < 576*512/8 = 36864
  int row = gid >> 6;
  int c0 = (gid & 63) * 8;
  float s[8] = {0.f, 0.f, 0.f, 0.f, 0.f, 0.f, 0.f, 0.f};
  const u16* p = partials + (size_t)row * HIDN + c0;
  for (int z = 0; z < KSPLIT; ++z) {
    ushort8_t v = *(const ushort8_t*)(p + (size_t)z * (M_ROWS * HIDN));
#pragma unroll
    for (int j = 0; j < 8; ++j) s[j] += bf2f(v[j]);
  }
  float4 o0, o1;
  const float* bi = bias + c0;
  o0.x = fmaxf(s[0] + bi[0], 0.f); o0.y = fmaxf(s[1] + bi[1], 0.f);
  o0.z = fmaxf(s[2] + bi[2], 0.f); o0.w = fmaxf(s[3] + bi[3], 0.f);
  o1.x = fmaxf(s[4] + bi[4], 0.f); o1.y = fmaxf(s[5] + bi[5], 0.f);
  o1.z = fmaxf(s[6] + bi[6], 0.f); o1.w = fmaxf(s[7] + bi[7], 0.f);
  float* dst = feats + (size_t)row * HIDN + c0;
  *(float4*)dst = o0;
  *(float4*)(dst + 4) = o1;
}

// ---------------- kernel 6: all heads, one wave per output dot -------------
__device__ __forceinline__ float wave_red(float s) {
#pragma unroll
  for (int off = 32; off > 0; off >>= 1) s += __shfl_down(s, off);
  return s;
}

__device__ __forceinline__ float dot512(const float* __restrict__ f,
                                        const float* __restrict__ w, int lane) {
  const float4* f4 = (const float4*)f;
  const float4* w4 = (const float4*)w;
  float4 x0 = f4[lane], y0 = w4[lane];
  float4 x1 = f4[lane + 64], y1 = w4[lane + 64];
  return x0.x * y0.x + x0.y * y0.y + x0.z * y0.z + x0.w * y0.w +
         x1.x * y1.x + x1.y * y1.y + x1.z * y1.z + x1.w * y1.w;
}

__global__ __launch_bounds__(256) void k_heads(const float* __restrict__ feats,
                                               const float* __restrict__ pred,
                                               const float* __restrict__ cW,
                                               const float* __restrict__ cb,
                                               const float* __restrict__ pW,
                                               const float* __restrict__ pb,
                                               const float* __restrict__ lW,
                                               const float* __restrict__ lb,
                                               const float* __restrict__ gW,
                                               const float* __restrict__ gb,
                                               const int* __restrict__ lidx,
                                               const int* __restrict__ gidx,
                                               float* __restrict__ out) {
  int wid = blockIdx.x * 4 + (threadIdx.x >> 6);   // 0..4639
  int lane = threadIdx.x & 63;
  float sum = 0.f;

  if (wid < 1664) {                 // refined (B,26,4)
    int b = wid / 104, rr = wid % 104, s = rr >> 2, o = rr & 3;
    sum = dot512(feats + (size_t)(b * NBOX + s) * HIDN,
                 cW + (size_t)(s * 4 + o) * HIDN, lane);
    sum = wave_red(sum);
    if (lane == 0) {
      const float* p = pred + (size_t)(b * SS + s) * 4;
      float wdt = p[2] - p[0], hgt = p[3] - p[1];
      float whv = (o & 1) ? hgt : wdt;
      out[wid] = p[o] + (sum + cb[s * 4 + o]) * whv;
    }
  } else if (wid < 2080) {          // presence (B,26)
    int i = wid - 1664;
    int b = i / 26, s = i % 26;
    sum = dot512(feats + (size_t)(b * NBOX + s) * HIDN,
                 pW + (size_t)s * HIDN, lane);
    sum = wave_red(sum);
    if (lane == 0) out[1664 + i] = sum + pb[s];
  } else if (wid < 3616) {          // loc (B,12,8)
    int i = wid - 2080;
    int b = i / 96, rr = i % 96, l = rr >> 3, o = rr & 7;
    sum = dot512(feats + (size_t)(b * NBOX + lidx[l]) * HIDN,
                 lW + (size_t)(l * 8 + o) * HIDN, lane);
    sum = wave_red(sum);
    if (lane == 0) out[2080 + b * 160 + rr] = sum + lb[l * 8 + o];
  } else {                          // grp (B,4,16), K = 6*512
    int i = wid - 3616;
    int b = i / 64, rr = i % 64, g = rr >> 4, o = rr & 15;
    const float* w = gW + (size_t)(g * 16 + o) * 3072;
#pragma unroll
    for (int jj = 0; jj < 6; ++jj) {
      sum += dot512(feats + (size_t)(b * NBOX + gidx[g * 6 + jj]) * HIDN,
                    w + jj * 512, lane);
    }
    sum = wave_red(sum);
    if (lane == 0) out[2080 + b * 160 + 96 + rr] = sum + gb[g * 16 + o];
  }
}

// ---------------------------------------------------------------------------
extern "C" void kernel_launch(void* const* d_in, const int* in_sizes, int n_in,
                              void* d_out, int out_size, void* d_ws, size_t ws_size,
                              hipStream_t stream) {
  const float* lf      = (const float*)d_in[0];
  const float* pred    = (const float*)d_in[1];
  const float* roiW    = (const float*)d_in[2];
  const float* roiB    = (const float*)d_in[3];
  const float* cW      = (const float*)d_in[4];
  const float* cb      = (const float*)d_in[5];
  const float* pW      = (const float*)d_in[6];
  const float* pb      = (const float*)d_in[7];
  const float* lW      = (const float*)d_in[8];
  const float* lb      = (const float*)d_in[9];
  const float* gW      = (const float*)d_in[10];
  const float* gb      = (const float*)d_in[11];
  const int*   lidx    = (const int*)d_in[12];
  const int*   gidx    = (const int*)d_in[13];
  float* out = (float*)d_out;

  char* ws = (char*)d_ws;
  // region 0: lf_t (16.8 MB) then reused by partials bf16 (33.0 MB = 56*576*512*2)
  u16*   lf_t     = (u16*)ws;
  u16*   partials = (u16*)ws;
  u16*   Wb2   = (u16*)(ws + 33030144);                 // 25,690,112 B
  u16*   flat2 = (u16*)(ws + 33030144 + 25690112);      // 28,901,376 B
  float* feats = (float*)(ws + 33030144 + 25690112 + 28901376); // 1,179,648 B

  k_transpose_lf<<<dim3(8, 32, 16), 256, 0, stream>>>(lf, lf_t);
  k_convert_w<<<HIDN, 256, 0, stream>>>(roiW, Wb2);
  k_roi<<<576, 512, 0, stream>>>(lf_t, pred, flat2);
  // NOTE: partials aliases lf_t's region; k_roi (last reader of lf_t) is
  // stream-ordered before k_gemm (first writer of partials).
  k_gemm<<<1120, 256, 0, stream>>>(flat2, Wb2, partials);
  k_reduce<<<(M_ROWS * HIDN / 8) / 256, 256, 0, stream>>>(partials, roiB, feats);
  k_heads<<<1160, 256, 0, stream>>>(feats, pred, cW, cb, pW, pb, lW, lb, gW, gb,
                                    lidx, gidx, out);
}

// Round 10
// 200.872 us; speedup vs baseline: 1.2369x; 1.0846x over previous
//
#include <hip/hip_runtime.h>

typedef unsigned short u16;
typedef __attribute__((ext_vector_type(8))) short short8;
typedef __attribute__((ext_vector_type(8))) unsigned short ushort8_t;
typedef __attribute__((ext_vector_type(4))) float f32x4;
typedef __attribute__((ext_vector_type(2))) float v2f;

#define BATCH   16
#define CCH     512
#define NBOX    36
#define SS      26
#define INDIM   25088   // 512*49
#define HIDN    512
#define M_ROWS  416     // BATCH*26 — boxes n>=26 never reach an output (R9)
#define KSPLIT  56
#define KITERS  7       // per split, BK=64 -> 56*7*64 = 25088
#define NKB     392     // total K-blocks of 64 (pixel-major k = p*512 + c)

__device__ __forceinline__ u16 f2bf(float f) {
  unsigned u = __float_as_uint(f);
  u += 0x7FFF + ((u >> 16) & 1);   // RNE
  return (u16)(u >> 16);
}
__device__ __forceinline__ float bf2f(u16 h) {
  return __uint_as_float(((unsigned)h) << 16);
}
__device__ __forceinline__ v2f bf2x2(u16 a, u16 b) {
  v2f r;
  r.x = __uint_as_float(((unsigned)a) << 16);
  r.y = __uint_as_float(((unsigned)b) << 16);
  return r;
}

// ---------------- kernel 1: transpose lf (B,C,H,W) f32 -> (B,HW,C) bf16 ----
__global__ __launch_bounds__(256) void k_transpose_lf(const float* __restrict__ in,
                                                      u16* __restrict__ out) {
  __shared__ u16 t[32][66];
  int b = blockIdx.z, y = blockIdx.y, ct = blockIdx.x;  // c0 = ct*64
  int tid = threadIdx.x;

  int cl = tid >> 2;            // 0..63 channel within tile
  int xq = (tid & 3) * 8;       // 8 consecutive x
  const float* src = in + ((size_t)(b * CCH + ct * 64 + cl) * 1024) + y * 32 + xq;
  float4 v0 = *(const float4*)src;
  float4 v1 = *(const float4*)(src + 4);
  t[xq + 0][cl] = f2bf(v0.x); t[xq + 1][cl] = f2bf(v0.y);
  t[xq + 2][cl] = f2bf(v0.z); t[xq + 3][cl] = f2bf(v0.w);
  t[xq + 4][cl] = f2bf(v1.x); t[xq + 5][cl] = f2bf(v1.y);
  t[xq + 6][cl] = f2bf(v1.z); t[xq + 7][cl] = f2bf(v1.w);
  __syncthreads();

  int xl = tid >> 3;            // 0..31
  int cq = (tid & 7) * 8;       // 8 consecutive channels
  ushort8_t o;
#pragma unroll
  for (int i = 0; i < 8; ++i) o[i] = t[xl][cq + i];
  *(ushort8_t*)(out + ((size_t)b * 1024 + y * 32 + xl) * CCH + ct * 64 + cq) = o;
}

// ---------------- kernel 2: roi_fc_W f32 -> Wb2[kb][h][64] bf16 ------------
#define WPAD 532
__global__ __launch_bounds__(256) void k_convert_w(const float* __restrict__ in,
                                                   u16* __restrict__ out) {
  __shared__ u16 s[49 * WPAD];   // 52136 B
  int h = blockIdx.x;
  int tid = threadIdx.x;
  const float4* src = (const float4*)(in + (size_t)h * INDIM);  // 6272 float4
  for (int i = tid; i < 6272; i += 256) {
    float4 v = src[i];
    int k = i * 4;
#pragma unroll
    for (int j = 0; j < 4; ++j) {
      int kk = k + j;
      int c = kk / 49;          // const divide -> magic mul
      int p = kk - c * 49;
      s[p * WPAD + c] = f2bf((&v.x)[j]);
    }
  }
  __syncthreads();
  // 3136 ushort8 chunks: q -> p = q>>6, c0 = (q&63)*8
  for (int q = tid; q < 3136; q += 256) {
    int p = q >> 6;
    int c0 = (q & 63) * 8;
    const u16* sp = &s[p * WPAD + c0];
    ushort8_t o;
#pragma unroll
    for (int i = 0; i < 8; ++i) o[i] = sp[i];
    int kb = p * 8 + (c0 >> 6);
    int col = c0 & 63;
    *(ushort8_t*)(out + ((size_t)kb * HIDN + h) * 64 + col) = o;
  }
}

// ---------------- kernel 3: ROI align -> flat2[kb][row][64] bf16 -----------
// v6: only boxes n<26 (R9: rows 26..35 never reach an output). 416 blocks,
// XCD-locality swizzle retained: XCD (bid&7) owns images {2*xcd, 2*xcd+1}
// (52 boxes), keeping taps in the local 4 MB L2.
__global__ __launch_bounds__(512) void k_roi(const u16* __restrict__ lf_t,
                                             const float* __restrict__ pred,
                                             u16* __restrict__ flat2) {
  __shared__ int   s_ylo[14], s_yhi[14], s_xlo[14], s_xhi[14];
  __shared__ float s_wyl[14], s_wyh[14], s_wxl[14], s_wxh[14];

  int bid = blockIdx.x;          // 0..415
  int xcd = bid & 7;
  int s = bid >> 3;              // 0..51
  int b = xcd * 2 + (s >= 26 ? 1 : 0);
  int n = (s >= 26) ? s - 26 : s;      // always < 26
  int blk = b * 26 + n;          // output row in M=416 space
  int t = threadIdx.x;

  if (t < 28) {
    bool isY = t < 14;
    int j = isY ? t : t - 14;
    const float* p = pred + ((size_t)(b * SS + n)) * 4;
    float c0 = p[0], c1 = p[1], c2 = p[2], c3 = p[3];
    float lo1 = (isY ? c1 : c0) * 32.f;
    float hi1 = (isY ? c3 : c2) * 32.f;
    float sz = fmaxf(hi1 - lo1, 1.f);
    float bs = sz * (1.f / 7.f);
    float off = (float)(j >> 1) + 0.25f + 0.5f * (float)(j & 1);
    float pos = lo1 + off * bs;
    bool valid = (pos > -1.f) && (pos < 32.f);
    float tc = fminf(fmaxf(pos, 0.f), 31.f);
    int lo = (int)floorf(tc);
    int hi = min(lo + 1, 31);
    float fr = tc - (float)lo;
    float wl = valid ? (1.f - fr) : 0.f;
    float wh = valid ? fr : 0.f;
    if (isY) { s_ylo[j] = lo; s_yhi[j] = hi; s_wyl[j] = wl; s_wyh[j] = wh; }
    else     { s_xlo[j] = lo; s_xhi[j] = hi; s_wxl[j] = wl; s_wxh[j] = wh; }
  }
  __syncthreads();

  int cg = t & 63;          // channel group: channels cg*8 .. cg*8+7
  int pg = t >> 6;          // pixel stripe: pixels pg, pg+8, ...
  const u16* base = lf_t + (size_t)b * 1024 * CCH + cg * 8;

  for (int p = pg; p < 49; p += 8) {
    int py = p / 7, px = p % 7;
    v2f a0 = {0.f, 0.f}, a1 = {0.f, 0.f}, a2 = {0.f, 0.f}, a3 = {0.f, 0.f};
#pragma unroll
    for (int sy = 0; sy < 2; ++sy) {
      int jy = 2 * py + sy;
      const u16* rlo = base + s_ylo[jy] * 32 * CCH;
      const u16* rhi = base + s_yhi[jy] * 32 * CCH;
      float wyl = s_wyl[jy], wyh = s_wyh[jy];
#pragma unroll
      for (int sx = 0; sx < 2; ++sx) {
        int jx = 2 * px + sx;
        int xl = s_xlo[jx] * CCH, xh = s_xhi[jx] * CCH;
        v2f wll = {wyl * s_wxl[jx], wyl * s_wxl[jx]};
        v2f wlh = {wyl * s_wxh[jx], wyl * s_wxh[jx]};
        v2f whl = {wyh * s_wxl[jx], wyh * s_wxl[jx]};
        v2f whh = {wyh * s_wxh[jx], wyh * s_wxh[jx]};
        ushort8_t vll = *(const ushort8_t*)(rlo + xl);
        ushort8_t vlh = *(const ushort8_t*)(rlo + xh);
        ushort8_t vhl = *(const ushort8_t*)(rhi + xl);
        ushort8_t vhh = *(const ushort8_t*)(rhi + xh);
        a0 += wll * bf2x2(vll[0], vll[1]) + wlh * bf2x2(vlh[0], vlh[1])
            + whl * bf2x2(vhl[0], vhl[1]) + whh * bf2x2(vhh[0], vhh[1]);
        a1 += wll * bf2x2(vll[2], vll[3]) + wlh * bf2x2(vlh[2], vlh[3])
            + whl * bf2x2(vhl[2], vhl[3]) + whh * bf2x2(vhh[2], vhh[3]);
        a2 += wll * bf2x2(vll[4], vll[5]) + wlh * bf2x2(vlh[4], vlh[5])
            + whl * bf2x2(vhl[4], vhl[5]) + whh * bf2x2(vhh[4], vhh[5]);
        a3 += wll * bf2x2(vll[6], vll[7]) + wlh * bf2x2(vlh[6], vlh[7])
            + whl * bf2x2(vhl[6], vhl[7]) + whh * bf2x2(vhh[6], vhh[7]);
      }
    }
    ushort8_t o;
    o[0] = f2bf(a0.x * 0.25f); o[1] = f2bf(a0.y * 0.25f);
    o[2] = f2bf(a1.x * 0.25f); o[3] = f2bf(a1.y * 0.25f);
    o[4] = f2bf(a2.x * 0.25f); o[5] = f2bf(a2.y * 0.25f);
    o[6] = f2bf(a3.x * 0.25f); o[7] = f2bf(a3.y * 0.25f);
    int kb = p * 8 + (cg >> 3);
    int col = (cg & 7) * 8;
    *(ushort8_t*)(flat2 + ((size_t)kb * M_ROWS + blk) * 64 + col) = o;
  }
}

// ---------------- kernel 4: GEMM, split-K, bf16 MFMA -----------------------
// v9: M=416 (28% fewer rows). R8 structure retained: 128x128 LDS tile,
// register pipeline, XOR swizzle, bf16 partials, XCD-owner z-mapping.
// 896 blocks = 8 XCDs x 7 z x 16 (4 M-tiles x 4 N-tiles); M tail (rows
// 416..511 of tileM0=384) handled by row-clamped loads + guarded stores.
__global__ __launch_bounds__(256) void k_gemm(const u16* __restrict__ flat2,
                                              const u16* __restrict__ Wb2,
                                              u16* __restrict__ partials) {
  __shared__ u16 As[128 * 64];   // 16 KB
  __shared__ u16 Bs[128 * 64];   // 16 KB

  int tid = threadIdx.x;
  int wave = tid >> 6, lane = tid & 63;
  int wm = wave >> 1, wn = wave & 1;
  int quad = lane >> 4, r = lane & 15;
  int xb = r & 7;                       // read-side XOR key

  // XCD-owner decode: 896 blocks = 8 XCDs x 7 z x 16 (x,y)
  int bid = blockIdx.x;
  int xcd = bid & 7;
  int slot = bid >> 3;                  // 0..111
  int z = xcd * 7 + (slot >> 4);        // 0..55
  int xy = slot & 15;
  int tileN0 = (xy & 3) * 128;
  int tileM0 = (xy >> 2) * 128;
  int kb0 = z * KITERS;

  size_t aoff[4], boff[4];
  int    ldso[4];
#pragma unroll
  for (int t = 0; t < 4; ++t) {
    int chunk = (wave * 4 + t) * 64 + lane;
    int row = chunk >> 3;
    int lc = chunk & 7;
    ldso[t] = row * 64 + ((lc ^ (row & 7)) << 3);
    int grow = min(tileM0 + row, M_ROWS - 1);     // clamp M tail
    aoff[t] = ((size_t)kb0 * M_ROWS + grow) * 64 + lc * 8;
    boff[t] = ((size_t)kb0 * HIDN + tileN0 + row) * 64 + lc * 8;
  }

  f32x4 acc[4][4];
#pragma unroll
  for (int mi = 0; mi < 4; ++mi)
#pragma unroll
    for (int ni = 0; ni < 4; ++ni) acc[mi][ni] = (f32x4){0.f, 0.f, 0.f, 0.f};

  short8 ra[4], rb[4];
#pragma unroll
  for (int t = 0; t < 4; ++t) {
    ra[t] = *(const short8*)(flat2 + aoff[t]);
    rb[t] = *(const short8*)(Wb2 + boff[t]);
  }

  for (int kt = 0; kt < KITERS; ++kt) {
    // commit current registers to LDS (vmcnt wait lands here, overlapped)
#pragma unroll
    for (int t = 0; t < 4; ++t) {
      *(short8*)&As[ldso[t]] = ra[t];
      *(short8*)&Bs[ldso[t]] = rb[t];
    }
    __syncthreads();

    // issue next tile's global loads (stay in flight through compute)
    if (kt + 1 < KITERS) {
      size_t ak = (size_t)(kt + 1) * (M_ROWS * 64);
      size_t bk = (size_t)(kt + 1) * (HIDN * 64);
#pragma unroll
      for (int t = 0; t < 4; ++t) {
        ra[t] = *(const short8*)(flat2 + aoff[t] + ak);
        rb[t] = *(const short8*)(Wb2 + boff[t] + bk);
      }
    }

    // compute on the committed tile
#pragma unroll
    for (int kk = 0; kk < 64; kk += 32) {
      int k8 = kk >> 3;                 // 0 or 4
      int pc = ((k8 + quad) ^ xb) << 3; // physical column (u16 units)
      short8 af[4], bfr[4];
#pragma unroll
      for (int mi = 0; mi < 4; ++mi)
        af[mi] = *(const short8*)&As[(wm * 64 + mi * 16 + r) * 64 + pc];
#pragma unroll
      for (int ni = 0; ni < 4; ++ni)
        bfr[ni] = *(const short8*)&Bs[(wn * 64 + ni * 16 + r) * 64 + pc];
#pragma unroll
      for (int mi = 0; mi < 4; ++mi)
#pragma unroll
        for (int ni = 0; ni < 4; ++ni)
          acc[mi][ni] = __builtin_amdgcn_mfma_f32_16x16x32_bf16(
              af[mi], bfr[ni], acc[mi][ni], 0, 0, 0);
    }
    __syncthreads();
  }

  u16* part = partials + (size_t)z * (M_ROWS * HIDN);
#pragma unroll
  for (int mi = 0; mi < 4; ++mi)
#pragma unroll
    for (int ni = 0; ni < 4; ++ni) {
      int row0 = tileM0 + wm * 64 + mi * 16 + quad * 4;
      int col = tileN0 + wn * 64 + ni * 16 + r;
#pragma unroll
      for (int reg = 0; reg < 4; ++reg) {
        int row = row0 + reg;
        if (row < M_ROWS) part[(size_t)row * HIDN + col] = f2bf(acc[mi][ni][reg]);
      }
    }
}

// ---------------- kernel 5: reduce split-K(bf16) + bias + relu -> feats ----
__global__ __launch_bounds__(256) void k_reduce(const u16* __restrict__ partials,
                                                const float* __restrict__ bias,
                                                float* __restrict__ feats) {
  int gid = blockIdx.x * 256 + threadIdx.x;   // < 416*512/8 = 26624
  int row = gid >> 6;
  int c0 = (gid & 63) * 8;
  float s[8] = {0.f, 0.f, 0.f, 0.f, 0.f, 0.f, 0.f, 0.f};
  const u16* p = partials + (size_t)row * HIDN + c0;
  for (int z = 0; z < KSPLIT; ++z) {
    ushort8_t v = *(const ushort8_t*)(p + (size_t)z * (M_ROWS * HIDN));
#pragma unroll
    for (int j = 0; j < 8; ++j) s[j] += bf2f(v[j]);
  }
  float4 o0, o1;
  const float* bi = bias + c0;
  o0.x = fmaxf(s[0] + bi[0], 0.f); o0.y = fmaxf(s[1] + bi[1], 0.f);
  o0.z = fmaxf(s[2] + bi[2], 0.f); o0.w = fmaxf(s[3] + bi[3], 0.f);
  o1.x = fmaxf(s[4] + bi[4], 0.f); o1.y = fmaxf(s[5] + bi[5], 0.f);
  o1.z = fmaxf(s[6] + bi[6], 0.f); o1.w = fmaxf(s[7] + bi[7], 0.f);
  float* dst = feats + (size_t)row * HIDN + c0;
  *(float4*)dst = o0;
  *(float4*)(dst + 4) = o1;
}

// ---------------- kernel 6: all heads, one wave per output dot -------------
// feats rows are now (b*26 + n), n<26.
__device__ __forceinline__ float wave_red(float s) {
#pragma unroll
  for (int off = 32; off > 0; off >>= 1) s += __shfl_down(s, off);
  return s;
}

__device__ __forceinline__ float dot512(const float* __restrict__ f,
                                        const float* __restrict__ w, int lane) {
  const float4* f4 = (const float4*)f;
  const float4* w4 = (const float4*)w;
  float4 x0 = f4[lane], y0 = w4[lane];
  float4 x1 = f4[lane + 64], y1 = w4[lane + 64];
  return x0.x * y0.x + x0.y * y0.y + x0.z * y0.z + x0.w * y0.w +
         x1.x * y1.x + x1.y * y1.y + x1.z * y1.z + x1.w * y1.w;
}

__global__ __launch_bounds__(256) void k_heads(const float* __restrict__ feats,
                                               const float* __restrict__ pred,
                                               const float* __restrict__ cW,
                                               const float* __restrict__ cb,
                                               const float* __restrict__ pW,
                                               const float* __restrict__ pb,
                                               const float* __restrict__ lW,
                                               const float* __restrict__ lb,
                                               const float* __restrict__ gW,
                                               const float* __restrict__ gb,
                                               const int* __restrict__ lidx,
                                               const int* __restrict__ gidx,
                                               float* __restrict__ out) {
  int wid = blockIdx.x * 4 + (threadIdx.x >> 6);   // 0..4639
  int lane = threadIdx.x & 63;
  float sum = 0.f;

  if (wid < 1664) {                 // refined (B,26,4)
    int b = wid / 104, rr = wid % 104, s = rr >> 2, o = rr & 3;
    sum = dot512(feats + (size_t)(b * 26 + s) * HIDN,
                 cW + (size_t)(s * 4 + o) * HIDN, lane);
    sum = wave_red(sum);
    if (lane == 0) {
      const float* p = pred + (size_t)(b * SS + s) * 4;
      float wdt = p[2] - p[0], hgt = p[3] - p[1];
      float whv = (o & 1) ? hgt : wdt;
      out[wid] = p[o] + (sum + cb[s * 4 + o]) * whv;
    }
  } else if (wid < 2080) {          // presence (B,26)
    int i = wid - 1664;
    int b = i / 26, s = i % 26;
    sum = dot512(feats + (size_t)(b * 26 + s) * HIDN,
                 pW + (size_t)s * HIDN, lane);
    sum = wave_red(sum);
    if (lane == 0) out[1664 + i] = sum + pb[s];
  } else if (wid < 3616) {          // loc (B,12,8)
    int i = wid - 2080;
    int b = i / 96, rr = i % 96, l = rr >> 3, o = rr & 7;
    sum = dot512(feats + (size_t)(b * 26 + lidx[l]) * HIDN,
                 lW + (size_t)(l * 8 + o) * HIDN, lane);
    sum = wave_red(sum);
    if (lane == 0) out[2080 + b * 160 + rr] = sum + lb[l * 8 + o];
  } else {                          // grp (B,4,16), K = 6*512
    int i = wid - 3616;
    int b = i / 64, rr = i % 64, g = rr >> 4, o = rr & 15;
    const float* w = gW + (size_t)(g * 16 + o) * 3072;
#pragma unroll
    for (int jj = 0; jj < 6; ++jj) {
      sum += dot512(feats + (size_t)(b * 26 + gidx[g * 6 + jj]) * HIDN,
                    w + jj * 512, lane);
    }
    sum = wave_red(sum);
    if (lane == 0) out[2080 + b * 160 + 96 + rr] = sum + gb[g * 16 + o];
  }
}

// ---------------------------------------------------------------------------
extern "C" void kernel_launch(void* const* d_in, const int* in_sizes, int n_in,
                              void* d_out, int out_size, void* d_ws, size_t ws_size,
                              hipStream_t stream) {
  const float* lf      = (const float*)d_in[0];
  const float* pred    = (const float*)d_in[1];
  const float* roiW    = (const float*)d_in[2];
  const float* roiB    = (const float*)d_in[3];
  const float* cW      = (const float*)d_in[4];
  const float* cb      = (const float*)d_in[5];
  const float* pW      = (const float*)d_in[6];
  const float* pb      = (const float*)d_in[7];
  const float* lW      = (const float*)d_in[8];
  const float* lb      = (const float*)d_in[9];
  const float* gW      = (const float*)d_in[10];
  const float* gb      = (const float*)d_in[11];
  const int*   lidx    = (const int*)d_in[12];
  const int*   gidx    = (const int*)d_in[13];
  float* out = (float*)d_out;

  char* ws = (char*)d_ws;
  // region 0: lf_t (16.8 MB) then reused by partials bf16 (23.9 MB = 56*416*512*2)
  u16*   lf_t     = (u16*)ws;
  u16*   partials = (u16*)ws;
  u16*   Wb2   = (u16*)(ws + 33030144);                 // 25,690,112 B
  u16*   flat2 = (u16*)(ws + 33030144 + 25690112);      // 20,873,216 B used
  float* feats = (float*)(ws + 33030144 + 25690112 + 28901376); // 851,968 B used

  k_transpose_lf<<<dim3(8, 32, 16), 256, 0, stream>>>(lf, lf_t);
  k_convert_w<<<HIDN, 256, 0, stream>>>(roiW, Wb2);
  k_roi<<<M_ROWS, 512, 0, stream>>>(lf_t, pred, flat2);
  // NOTE: partials aliases lf_t's region; k_roi (last reader of lf_t) is
  // stream-ordered before k_gemm (first writer of partials).
  k_gemm<<<896, 256, 0, stream>>>(flat2, Wb2, partials);
  k_reduce<<<(M_ROWS * HIDN / 8) / 256, 256, 0, stream>>>(partials, roiB, feats);
  k_heads<<<1160, 256, 0, stream>>>(feats, pred, cW, cb, pW, pb, lW, lb, gW, gb,
                                    lidx, gidx, out);
}